// Round 1
// baseline (421.824 us; speedup 1.0000x reference)
//
#include <hip/hip_runtime.h>
#include <math.h>

// Sizes (fixed by the reference)
#define N_OBS    20000
#define N_OBS4   5000      // N_OBS/4
#define N_STATES 1024
#define N_ACT    64
#define SDIM     256
#define RFD      2048
#define DECAY    0.9f

typedef float v4f __attribute__((ext_vector_type(4)));

__device__ __forceinline__ v4f ld4(const float* p) {
    return *(const v4f*)p;
}
__device__ __forceinline__ v4f ntload4(const float* p) {
    return __builtin_nontemporal_load((const v4f*)p);
}

// ---------------- workspace layout (floats) ----------------
// zeroed region @0: score[1024], obs_acc[20000]
#define OFF_SCORE  0
#define OFF_OBSACC 1024
#define ZERO_CNT   (OFF_OBSACC + N_OBS)           // 21024 floats
#define OFF_S0RE   21024
#define OFF_S0IM   23072
#define OFF_S2RE   25120
#define OFF_S2IM   27168
#define OFF_WTS    29216
#define OFF_VWS    30240
#define OFF_COSQ   30496
#define OFF_SINQ   (OFF_COSQ + RFD*N_STATES)
#define WS_FLOATS  (OFF_SINQ + RFD*N_STATES)      // ~16.9 MB

// Fused kernel: blocks 0..511 = W@Q GEMM tiles (cos/sin), block 512 = v=V@action,
// blocks 513..2560 = state0 full-row dot products (one row d per block).
// Pass-1 M loads are NORMAL (not nt) so the tail of M stays resident in the
// 256 MB Infinity Cache for pass 2 (k_obs_acc), which walks rows in reverse.
#define NB_GEMM   512
#define NB_P1     RFD
#define NB_FUSED  (NB_GEMM + 1 + NB_P1)

__global__ __launch_bounds__(256) void k_fused(
    const float* __restrict__ Mre, const float* __restrict__ Mim,
    const float* __restrict__ obs,
    const float* __restrict__ W, const float* __restrict__ Q,
    const float* __restrict__ V, const float* __restrict__ action,
    float* __restrict__ cosQ, float* __restrict__ sinQ,
    float* __restrict__ s0re, float* __restrict__ s0im,
    float* __restrict__ vout)
{
    const int b = blockIdx.x;
    const int tid = threadIdx.x;

    if (b < NB_GEMM) {
        // ---- W@Q GEMM tile: theta -> cos/sin ----
        __shared__ float As[16][65];   // [k][m], +1 pad
        __shared__ float Bs[16][64];   // [k][n]
        const int tx = tid & 15;       // n-group (4 cols each)
        const int ty = tid >> 4;       // m-group (4 rows each)
        const int m0 = (b >> 4) * 64;  // 32 m-tiles
        const int n0 = (b & 15) * 64;  // 16 n-tiles
        float c[4][4] = {};
        for (int k0 = 0; k0 < SDIM; k0 += 16) {
            {   // load A: W[m0+m][k0+k]
                int k = tid & 15, mb = tid >> 4;
                #pragma unroll
                for (int j = 0; j < 4; j++)
                    As[k][mb + 16*j] = W[(size_t)(m0 + mb + 16*j) * SDIM + k0 + k];
            }
            {   // load B: Q[k0+k][n0+n]
                int n = tid & 63, kb = tid >> 6;
                #pragma unroll
                for (int j = 0; j < 4; j++)
                    Bs[kb + 4*j][n] = Q[(size_t)(k0 + kb + 4*j) * N_STATES + n0 + n];
            }
            __syncthreads();
            #pragma unroll
            for (int kk = 0; kk < 16; kk++) {
                float a[4], bb[4];
                #pragma unroll
                for (int i = 0; i < 4; i++) a[i] = As[kk][ty*4 + i];
                #pragma unroll
                for (int j = 0; j < 4; j++) bb[j] = Bs[kk][tx*4 + j];
                #pragma unroll
                for (int i = 0; i < 4; i++)
                    #pragma unroll
                    for (int j = 0; j < 4; j++)
                        c[i][j] += a[i] * bb[j];
            }
            __syncthreads();
        }
        #pragma unroll
        for (int i = 0; i < 4; i++) {
            int d = m0 + ty*4 + i;
            #pragma unroll
            for (int j = 0; j < 4; j++) {
                int s = n0 + tx*4 + j;
                float sn, cs;
                sincosf(c[i][j], &sn, &cs);
                cosQ[(size_t)d * N_STATES + s] = cs;
                sinQ[(size_t)d * N_STATES + s] = sn;
            }
        }
    } else if (b == NB_GEMM) {
        // ---- v = V @ action ----
        float acc = 0.f;
        for (int a = 0; a < N_ACT; a++) acc += V[tid * N_ACT + a] * action[a];
        vout[tid] = acc;
    } else {
        // ---- state0: full dot product for one row d ----
        const int d = b - (NB_GEMM + 1);
        const float* mr = Mre + (size_t)d * N_OBS;
        const float* mi = Mim + (size_t)d * N_OBS;
        const float4* ob = (const float4*)obs;
        float ar[4] = {0.f, 0.f, 0.f, 0.f}, ai[4] = {0.f, 0.f, 0.f, 0.f};
        int i = tid;
        #pragma unroll 4
        for (int it = 0; it < 19; ++it, i += 256) {   // 19*256 = 4864 <= 5000
            float4 o = ob[i];
            v4f a = ld4(mr + 4 * (size_t)i);
            v4f m = ld4(mi + 4 * (size_t)i);
            ar[it & 3] += a.x*o.x + a.y*o.y + a.z*o.z + a.w*o.w;
            ai[it & 3] += m.x*o.x + m.y*o.y + m.z*o.z + m.w*o.w;
        }
        if (i < N_OBS4) {                              // tail: threads 0..135
            float4 o = ob[i];
            v4f a = ld4(mr + 4 * (size_t)i);
            v4f m = ld4(mi + 4 * (size_t)i);
            ar[3] += a.x*o.x + a.y*o.y + a.z*o.z + a.w*o.w;
            ai[3] += m.x*o.x + m.y*o.y + m.z*o.z + m.w*o.w;
        }
        float arr = (ar[0] + ar[1]) + (ar[2] + ar[3]);
        float aii = (ai[0] + ai[1]) + (ai[2] + ai[3]);
        #pragma unroll
        for (int off = 32; off > 0; off >>= 1) {
            arr += __shfl_down(arr, off);
            aii += __shfl_down(aii, off);
        }
        __shared__ float pr[4], pi[4];
        const int wave = tid >> 6, lane = tid & 63;
        if (lane == 0) { pr[wave] = arr; pi[wave] = aii; }
        __syncthreads();
        if (tid == 0) {
            s0re[d] = pr[0] + pr[1] + pr[2] + pr[3];
            s0im[d] = pi[0] + pi[1] + pi[2] + pi[3];
        }
    }
}

// K3: fused phase + score. Per block: rotate 32 rows of s0 by e^{i W@v}
// (8 threads per row, coalesced float4 reads of W), then
// score[s] += sum_d cos[d,s]*s1re[d] + sin[d,s]*s1im[d]. grid (4,64).
__global__ __launch_bounds__(256) void k_score(
    const float* __restrict__ cosQ, const float* __restrict__ sinQ,
    const float* __restrict__ W, const float* __restrict__ vws,
    const float* __restrict__ s0re, const float* __restrict__ s0im,
    float* __restrict__ score)
{
    __shared__ float s1r_s[32], s1i_s[32];
    const int tid = threadIdx.x;
    const int d0 = blockIdx.y * 32;
    {
        const int r = tid >> 3, g = tid & 7;   // row r, 32-float segment g
        const float4* wv4 = (const float4*)(W + (size_t)(d0 + r) * SDIM + g * 32);
        const float4* vv4 = (const float4*)(vws + g * 32);
        float th = 0.f;
        #pragma unroll
        for (int j = 0; j < 8; j++) {
            float4 wv = wv4[j], vv = vv4[j];
            th += wv.x*vv.x + wv.y*vv.y + wv.z*vv.z + wv.w*vv.w;
        }
        th += __shfl_xor(th, 4);
        th += __shfl_xor(th, 2);
        th += __shfl_xor(th, 1);
        if (g == 0) {
            float sn, cs;
            sincosf(th, &sn, &cs);
            float re = s0re[d0 + r], im = s0im[d0 + r];
            s1r_s[r] = re * cs - im * sn;
            s1i_s[r] = re * sn + im * cs;
        }
    }
    __syncthreads();
    const int s = blockIdx.x * 256 + tid;
    float acc = 0.f;
    #pragma unroll 4
    for (int j = 0; j < 32; j++) {
        int d = d0 + j;
        acc += cosQ[(size_t)d * N_STATES + s] * s1r_s[j]
             + sinQ[(size_t)d * N_STATES + s] * s1i_s[j];
    }
    atomicAdd(&score[s], acc);
}

// K4: weights = softmax(score / 2048), 1024 entries, single block of 256
__global__ __launch_bounds__(256) void k_softmax_w(
    const float* __restrict__ score, float* __restrict__ wts)
{
    __shared__ float red[256];
    const int tid = threadIdx.x;
    const float scale = 1.f / (float)RFD;
    float4 v = ((const float4*)score)[tid];
    v.x *= scale; v.y *= scale; v.z *= scale; v.w *= scale;
    float mx = fmaxf(fmaxf(v.x, v.y), fmaxf(v.z, v.w));
    red[tid] = mx; __syncthreads();
    for (int s = 128; s > 0; s >>= 1) {
        if (tid < s) red[tid] = fmaxf(red[tid], red[tid+s]);
        __syncthreads();
    }
    mx = red[0]; __syncthreads();
    float4 e;
    e.x = expf(v.x - mx); e.y = expf(v.y - mx);
    e.z = expf(v.z - mx); e.w = expf(v.w - mx);
    red[tid] = e.x + e.y + e.z + e.w; __syncthreads();
    for (int s = 128; s > 0; s >>= 1) {
        if (tid < s) red[tid] += red[tid+s];
        __syncthreads();
    }
    const float inv = 1.f / red[0];
    e.x *= inv; e.y *= inv; e.z *= inv; e.w *= inv;
    ((float4*)wts)[tid] = e;
}

// K5: state2 = phi_Q @ weights. Block per row d.
__global__ __launch_bounds__(256) void k_state2(
    const float* __restrict__ cosQ, const float* __restrict__ sinQ,
    const float* __restrict__ wts,
    float* __restrict__ s2re, float* __restrict__ s2im)
{
    __shared__ float r1[256], r2[256];
    const int d = blockIdx.x, tid = threadIdx.x;
    float4 w = ((const float4*)wts)[tid];
    float4 a = ((const float4*)(cosQ + (size_t)d * N_STATES))[tid];
    float4 b = ((const float4*)(sinQ + (size_t)d * N_STATES))[tid];
    r1[tid] = a.x*w.x + a.y*w.y + a.z*w.z + a.w*w.w;
    r2[tid] = b.x*w.x + b.y*w.y + b.z*w.z + b.w*w.w;
    __syncthreads();
    for (int s = 128; s > 0; s >>= 1) {
        if (tid < s) { r1[tid] += r1[tid+s]; r2[tid] += r2[tid+s]; }
        __syncthreads();
    }
    if (tid == 0) { s2re[d] = r1[0]; s2im[d] = r2[0]; }
}

// K6: obs_acc[o] += sum_{d in chunk of 64} Mre[d,o]*s2re[d] + Mim[d,o]*s2im[d]
// grid (20, 32), 256 threads. 64 rows/block => 4x fewer same-address atomics.
// Row chunks walked in REVERSE d order: pass 1 finished at high d, so those
// rows are the ones still resident in the Infinity Cache. nt loads (last use).
__global__ __launch_bounds__(256) void k_obs_acc(
    const float* __restrict__ Mre, const float* __restrict__ Mim,
    const float* __restrict__ s2re, const float* __restrict__ s2im,
    float* __restrict__ obs_acc)
{
    __shared__ float c_s[64], s_s[64];
    const int tid = threadIdx.x;
    const int dbase = (31 - (int)blockIdx.y) * 64;
    if (tid < 64) { c_s[tid] = s2re[dbase + tid]; s_s[tid] = s2im[dbase + tid]; }
    __syncthreads();
    const int idx = blockIdx.x * 256 + tid;   // float4 index into a row
    if (idx >= N_OBS4) return;
    float4 acc[4];
    #pragma unroll
    for (int u = 0; u < 4; u++) acc[u] = make_float4(0.f, 0.f, 0.f, 0.f);
    #pragma unroll 8
    for (int j = 0; j < 64; j++) {
        size_t base = ((size_t)(dbase + j) * N_OBS4 + idx) * 4;
        v4f a = ntload4(Mre + base);
        v4f b = ntload4(Mim + base);
        float cc = c_s[j], ss = s_s[j];
        acc[j & 3].x += a.x*cc + b.x*ss;
        acc[j & 3].y += a.y*cc + b.y*ss;
        acc[j & 3].z += a.z*cc + b.z*ss;
        acc[j & 3].w += a.w*cc + b.w*ss;
    }
    float4 t;
    t.x = (acc[0].x + acc[1].x) + (acc[2].x + acc[3].x);
    t.y = (acc[0].y + acc[1].y) + (acc[2].y + acc[3].y);
    t.z = (acc[0].z + acc[1].z) + (acc[2].z + acc[3].z);
    t.w = (acc[0].w + acc[1].w) + (acc[2].w + acc[3].w);
    atomicAdd(&obs_acc[idx*4 + 0], t.x);
    atomicAdd(&obs_acc[idx*4 + 1], t.y);
    atomicAdd(&obs_acc[idx*4 + 2], t.z);
    atomicAdd(&obs_acc[idx*4 + 3], t.w);
}

// K7: dot0 = Re(s0 . conj(s2)); out = softmax((0.9*obs_acc + obs*dot0)/2048).
__global__ __launch_bounds__(1024) void k_softmax_obs(
    const float* __restrict__ obs_acc, const float* __restrict__ obs,
    const float* __restrict__ s0re, const float* __restrict__ s0im,
    const float* __restrict__ s2re, const float* __restrict__ s2im,
    float* __restrict__ out)
{
    __shared__ float red[1024];
    const int tid = threadIdx.x;
    float dp = 0.f;
    #pragma unroll
    for (int i = 0; i < 2; i++) {
        int d = tid + i * 1024;
        dp += s0re[d] * s2re[d] + s0im[d] * s2im[d];
    }
    red[tid] = dp; __syncthreads();
    for (int s = 512; s > 0; s >>= 1) {
        if (tid < s) red[tid] += red[tid+s];
        __syncthreads();
    }
    const float d0 = red[0];
    __syncthreads();
    const float scale = 1.f / (float)RFD;
    float vals[20];
    float mx = -3.402823466e+38f;
    #pragma unroll
    for (int i = 0; i < 20; i++) {
        int idx = tid + i * 1024;
        if (idx < N_OBS) {
            float sc = (DECAY * obs_acc[idx] + obs[idx] * d0) * scale;
            vals[i] = sc;
            mx = fmaxf(mx, sc);
        } else vals[i] = -3.402823466e+38f;
    }
    red[tid] = mx; __syncthreads();
    for (int s = 512; s > 0; s >>= 1) {
        if (tid < s) red[tid] = fmaxf(red[tid], red[tid+s]);
        __syncthreads();
    }
    mx = red[0]; __syncthreads();
    float sum = 0.f;
    #pragma unroll
    for (int i = 0; i < 20; i++) {
        int idx = tid + i * 1024;
        if (idx < N_OBS) {
            vals[i] = expf(vals[i] - mx);
            sum += vals[i];
        }
    }
    red[tid] = sum; __syncthreads();
    for (int s = 512; s > 0; s >>= 1) {
        if (tid < s) red[tid] += red[tid+s];
        __syncthreads();
    }
    const float inv = 1.f / red[0];
    #pragma unroll
    for (int i = 0; i < 20; i++) {
        int idx = tid + i * 1024;
        if (idx < N_OBS) out[idx] = vals[i] * inv;
    }
}

extern "C" void kernel_launch(void* const* d_in, const int* in_sizes, int n_in,
                              void* d_out, int out_size, void* d_ws, size_t ws_size,
                              hipStream_t stream) {
    const float* Q      = (const float*)d_in[0];  // [256,1024]
    const float* V      = (const float*)d_in[1];  // [256,64]
    const float* W      = (const float*)d_in[2];  // [2048,256]
    const float* Mre    = (const float*)d_in[3];  // [2048,20000]
    const float* Mim    = (const float*)d_in[4];  // [2048,20000]
    const float* obs    = (const float*)d_in[5];  // [20000]
    const float* action = (const float*)d_in[6];  // [64]
    float* out = (float*)d_out;                   // [20000]
    float* ws  = (float*)d_ws;

    if (ws_size < (size_t)WS_FLOATS * sizeof(float)) return;

    float* score = ws + OFF_SCORE;
    float* oacc  = ws + OFF_OBSACC;
    float* s0re  = ws + OFF_S0RE;
    float* s0im  = ws + OFF_S0IM;
    float* s2re  = ws + OFF_S2RE;
    float* s2im  = ws + OFF_S2IM;
    float* wts   = ws + OFF_WTS;
    float* vws   = ws + OFF_VWS;
    float* cosQ  = ws + OFF_COSQ;
    float* sinQ  = ws + OFF_SINQ;

    // zero the atomic accumulators (score, obs_acc) in one contiguous memset
    hipMemsetAsync(ws, 0, (size_t)ZERO_CNT * sizeof(float), stream);

    k_fused<<<NB_FUSED, 256, 0, stream>>>(Mre, Mim, obs, W, Q, V, action,
                                          cosQ, sinQ, s0re, s0im, vws);
    k_score<<<dim3(4, 64), 256, 0, stream>>>(cosQ, sinQ, W, vws, s0re, s0im, score);
    k_softmax_w<<<1, 256, 0, stream>>>(score, wts);
    k_state2<<<RFD, 256, 0, stream>>>(cosQ, sinQ, wts, s2re, s2im);
    k_obs_acc<<<dim3(20, 32), 256, 0, stream>>>(Mre, Mim, s2re, s2im, oacc);
    k_softmax_obs<<<1, 1024, 0, stream>>>(oacc, obs, s0re, s0im, s2re, s2im, out);
}

// Round 2
// 414.751 us; speedup vs baseline: 1.0171x; 1.0171x over previous
//
#include <hip/hip_runtime.h>
#include <hip/hip_fp16.h>
#include <math.h>

// Sizes (fixed by the reference)
#define N_OBS    20000
#define N_OBS4   5000      // N_OBS/4
#define N_STATES 1024
#define N_ACT    64
#define SDIM     256
#define RFD      2048
#define DECAY    0.9f

typedef float v4f __attribute__((ext_vector_type(4)));

__device__ __forceinline__ v4f ld4(const float* p) {
    return *(const v4f*)p;
}
__device__ __forceinline__ v4f ntload4(const float* p) {
    return __builtin_nontemporal_load((const v4f*)p);
}

// pack (re,im) float4 pair into 8 fp16 (re0,im0,re1,im1,...) = 16 bytes
__device__ __forceinline__ uint4 pack8(v4f re, v4f im) {
    union { __half h[8]; uint4 u; } p;
    p.h[0] = __float2half_rn(re.x); p.h[1] = __float2half_rn(im.x);
    p.h[2] = __float2half_rn(re.y); p.h[3] = __float2half_rn(im.y);
    p.h[4] = __float2half_rn(re.z); p.h[5] = __float2half_rn(im.z);
    p.h[6] = __float2half_rn(re.w); p.h[7] = __float2half_rn(im.w);
    return p.u;
}

// ---------------- workspace layout (floats) ----------------
// zeroed region @0: score[1024], obs_acc[20000]
#define OFF_SCORE  0
#define OFF_OBSACC 1024
#define ZERO_CNT   (OFF_OBSACC + N_OBS)           // 21024 floats
#define OFF_S0RE   21024
#define OFF_S0IM   23072
#define OFF_S2RE   25120
#define OFF_S2IM   27168
#define OFF_WTS    29216
#define OFF_VWS    30240
#define OFF_COSQ   30496
#define OFF_SINQ   (OFF_COSQ + RFD*N_STATES)
#define OFF_MH     (OFF_SINQ + RFD*N_STATES)      // 4,224,800 (16B aligned)
#define MH_FLOATS  (RFD * N_OBS4 * 4)             // fp16 interleaved M copy, 164 MB
#define WS_BASE_FLOATS (OFF_MH)
#define WS_FP16_FLOATS (OFF_MH + MH_FLOATS)       // ~181 MB

// Fused kernel block map: [0,1024) = state0 row-pairs (stream M, emit fp16 copy),
// 1024 = v=V@action, (1024, 1536] = W@Q GEMM tiles (cos/sin).
// State0 blocks first so HBM streaming starts immediately; GEMM fills in.
#define NB_P1     (RFD / 2)
#define NB_GEMM   512
#define NB_FUSED  (NB_P1 + 1 + NB_GEMM)

__global__ __launch_bounds__(256) void k_fused(
    const float* __restrict__ Mre, const float* __restrict__ Mim,
    const float* __restrict__ obs,
    const float* __restrict__ W, const float* __restrict__ Q,
    const float* __restrict__ V, const float* __restrict__ action,
    float* __restrict__ cosQ, float* __restrict__ sinQ,
    float* __restrict__ s0re, float* __restrict__ s0im,
    float* __restrict__ vout, uint4* __restrict__ Mh, int writeMh)
{
    const int b = blockIdx.x;
    const int tid = threadIdx.x;

    if (b < NB_P1) {
        // ---- state0 for rows d0, d0+1: full-row dots; optionally emit fp16 copy ----
        const int d0 = b * 2;
        const float* mr0 = Mre + (size_t)d0 * N_OBS;
        const float* mi0 = Mim + (size_t)d0 * N_OBS;
        const float* mr1 = mr0 + N_OBS;
        const float* mi1 = mi0 + N_OBS;
        uint4* mh0 = Mh + (size_t)d0 * N_OBS4;
        uint4* mh1 = mh0 + N_OBS4;
        const float4* ob = (const float4*)obs;
        float a0r[2] = {0.f, 0.f}, a0i[2] = {0.f, 0.f};
        float a1r[2] = {0.f, 0.f}, a1i[2] = {0.f, 0.f};
        int i = tid;
        if (writeMh) {
            #pragma unroll 2
            for (int it = 0; it < 19; ++it, i += 256) {   // 19*256 = 4864
                float4 o = ob[i];
                v4f r0 = ntload4(mr0 + 4 * (size_t)i);
                v4f q0 = ntload4(mi0 + 4 * (size_t)i);
                v4f r1 = ntload4(mr1 + 4 * (size_t)i);
                v4f q1 = ntload4(mi1 + 4 * (size_t)i);
                mh0[i] = pack8(r0, q0);
                mh1[i] = pack8(r1, q1);
                a0r[it & 1] += r0.x*o.x + r0.y*o.y + r0.z*o.z + r0.w*o.w;
                a0i[it & 1] += q0.x*o.x + q0.y*o.y + q0.z*o.z + q0.w*o.w;
                a1r[it & 1] += r1.x*o.x + r1.y*o.y + r1.z*o.z + r1.w*o.w;
                a1i[it & 1] += q1.x*o.x + q1.y*o.y + q1.z*o.z + q1.w*o.w;
            }
            if (i < N_OBS4) {                              // tail: threads 0..135
                float4 o = ob[i];
                v4f r0 = ntload4(mr0 + 4 * (size_t)i);
                v4f q0 = ntload4(mi0 + 4 * (size_t)i);
                v4f r1 = ntload4(mr1 + 4 * (size_t)i);
                v4f q1 = ntload4(mi1 + 4 * (size_t)i);
                mh0[i] = pack8(r0, q0);
                mh1[i] = pack8(r1, q1);
                a0r[0] += r0.x*o.x + r0.y*o.y + r0.z*o.z + r0.w*o.w;
                a0i[0] += q0.x*o.x + q0.y*o.y + q0.z*o.z + q0.w*o.w;
                a1r[0] += r1.x*o.x + r1.y*o.y + r1.z*o.z + r1.w*o.w;
                a1i[0] += q1.x*o.x + q1.y*o.y + q1.z*o.z + q1.w*o.w;
            }
        } else {
            #pragma unroll 2
            for (int it = 0; it < 19; ++it, i += 256) {
                float4 o = ob[i];
                v4f r0 = ntload4(mr0 + 4 * (size_t)i);
                v4f q0 = ntload4(mi0 + 4 * (size_t)i);
                v4f r1 = ntload4(mr1 + 4 * (size_t)i);
                v4f q1 = ntload4(mi1 + 4 * (size_t)i);
                a0r[it & 1] += r0.x*o.x + r0.y*o.y + r0.z*o.z + r0.w*o.w;
                a0i[it & 1] += q0.x*o.x + q0.y*o.y + q0.z*o.z + q0.w*o.w;
                a1r[it & 1] += r1.x*o.x + r1.y*o.y + r1.z*o.z + r1.w*o.w;
                a1i[it & 1] += q1.x*o.x + q1.y*o.y + q1.z*o.z + q1.w*o.w;
            }
            if (i < N_OBS4) {
                float4 o = ob[i];
                v4f r0 = ntload4(mr0 + 4 * (size_t)i);
                v4f q0 = ntload4(mi0 + 4 * (size_t)i);
                v4f r1 = ntload4(mr1 + 4 * (size_t)i);
                v4f q1 = ntload4(mi1 + 4 * (size_t)i);
                a0r[0] += r0.x*o.x + r0.y*o.y + r0.z*o.z + r0.w*o.w;
                a0i[0] += q0.x*o.x + q0.y*o.y + q0.z*o.z + q0.w*o.w;
                a1r[0] += r1.x*o.x + r1.y*o.y + r1.z*o.z + r1.w*o.w;
                a1i[0] += q1.x*o.x + q1.y*o.y + q1.z*o.z + q1.w*o.w;
            }
        }
        float v0 = a0r[0] + a0r[1];
        float v1 = a0i[0] + a0i[1];
        float v2 = a1r[0] + a1r[1];
        float v3 = a1i[0] + a1i[1];
        #pragma unroll
        for (int off = 32; off > 0; off >>= 1) {
            v0 += __shfl_down(v0, off);
            v1 += __shfl_down(v1, off);
            v2 += __shfl_down(v2, off);
            v3 += __shfl_down(v3, off);
        }
        __shared__ float red[4][4];
        const int wave = tid >> 6, lane = tid & 63;
        if (lane == 0) {
            red[wave][0] = v0; red[wave][1] = v1;
            red[wave][2] = v2; red[wave][3] = v3;
        }
        __syncthreads();
        if (tid == 0) {
            float r0 = 0.f, i0 = 0.f, r1 = 0.f, i1 = 0.f;
            #pragma unroll
            for (int w = 0; w < 4; w++) {
                r0 += red[w][0]; i0 += red[w][1];
                r1 += red[w][2]; i1 += red[w][3];
            }
            s0re[d0] = r0; s0im[d0] = i0;
            s0re[d0 + 1] = r1; s0im[d0 + 1] = i1;
        }
    } else if (b == NB_P1) {
        // ---- v = V @ action ----
        float acc = 0.f;
        for (int a = 0; a < N_ACT; a++) acc += V[tid * N_ACT + a] * action[a];
        vout[tid] = acc;
    } else {
        // ---- W@Q GEMM tile: theta -> cos/sin ----
        const int g = b - (NB_P1 + 1);
        __shared__ float As[16][65];   // [k][m], +1 pad
        __shared__ float Bs[16][64];   // [k][n]
        const int tx = tid & 15;       // n-group (4 cols each)
        const int ty = tid >> 4;       // m-group (4 rows each)
        const int m0 = (g >> 4) * 64;  // 32 m-tiles
        const int n0 = (g & 15) * 64;  // 16 n-tiles
        float c[4][4] = {};
        for (int k0 = 0; k0 < SDIM; k0 += 16) {
            {   // load A: W[m0+m][k0+k]
                int k = tid & 15, mb = tid >> 4;
                #pragma unroll
                for (int j = 0; j < 4; j++)
                    As[k][mb + 16*j] = W[(size_t)(m0 + mb + 16*j) * SDIM + k0 + k];
            }
            {   // load B: Q[k0+k][n0+n]
                int n = tid & 63, kb = tid >> 6;
                #pragma unroll
                for (int j = 0; j < 4; j++)
                    Bs[kb + 4*j][n] = Q[(size_t)(k0 + kb + 4*j) * N_STATES + n0 + n];
            }
            __syncthreads();
            #pragma unroll
            for (int kk = 0; kk < 16; kk++) {
                float a[4], bb[4];
                #pragma unroll
                for (int i = 0; i < 4; i++) a[i] = As[kk][ty*4 + i];
                #pragma unroll
                for (int j = 0; j < 4; j++) bb[j] = Bs[kk][tx*4 + j];
                #pragma unroll
                for (int i = 0; i < 4; i++)
                    #pragma unroll
                    for (int j = 0; j < 4; j++)
                        c[i][j] += a[i] * bb[j];
            }
            __syncthreads();
        }
        #pragma unroll
        for (int i = 0; i < 4; i++) {
            int d = m0 + ty*4 + i;
            #pragma unroll
            for (int j = 0; j < 4; j++) {
                int s = n0 + tx*4 + j;
                float sn, cs;
                sincosf(c[i][j], &sn, &cs);
                cosQ[(size_t)d * N_STATES + s] = cs;
                sinQ[(size_t)d * N_STATES + s] = sn;
            }
        }
    }
}

// K3: fused phase + score. Per block: rotate 32 rows of s0 by e^{i W@v}
// (8 threads per row, coalesced float4 reads of W), then
// score[s] += sum_d cos[d,s]*s1re[d] + sin[d,s]*s1im[d]. grid (4,64).
__global__ __launch_bounds__(256) void k_score(
    const float* __restrict__ cosQ, const float* __restrict__ sinQ,
    const float* __restrict__ W, const float* __restrict__ vws,
    const float* __restrict__ s0re, const float* __restrict__ s0im,
    float* __restrict__ score)
{
    __shared__ float s1r_s[32], s1i_s[32];
    const int tid = threadIdx.x;
    const int d0 = blockIdx.y * 32;
    {
        const int r = tid >> 3, g = tid & 7;   // row r, 32-float segment g
        const float4* wv4 = (const float4*)(W + (size_t)(d0 + r) * SDIM + g * 32);
        const float4* vv4 = (const float4*)(vws + g * 32);
        float th = 0.f;
        #pragma unroll
        for (int j = 0; j < 8; j++) {
            float4 wv = wv4[j], vv = vv4[j];
            th += wv.x*vv.x + wv.y*vv.y + wv.z*vv.z + wv.w*vv.w;
        }
        th += __shfl_xor(th, 4);
        th += __shfl_xor(th, 2);
        th += __shfl_xor(th, 1);
        if (g == 0) {
            float sn, cs;
            sincosf(th, &sn, &cs);
            float re = s0re[d0 + r], im = s0im[d0 + r];
            s1r_s[r] = re * cs - im * sn;
            s1i_s[r] = re * sn + im * cs;
        }
    }
    __syncthreads();
    const int s = blockIdx.x * 256 + tid;
    float acc = 0.f;
    #pragma unroll 4
    for (int j = 0; j < 32; j++) {
        int d = d0 + j;
        acc += cosQ[(size_t)d * N_STATES + s] * s1r_s[j]
             + sinQ[(size_t)d * N_STATES + s] * s1i_s[j];
    }
    atomicAdd(&score[s], acc);
}

// K4: weights = softmax(score / 2048), 1024 entries, single block of 256
__global__ __launch_bounds__(256) void k_softmax_w(
    const float* __restrict__ score, float* __restrict__ wts)
{
    __shared__ float red[256];
    const int tid = threadIdx.x;
    const float scale = 1.f / (float)RFD;
    float4 v = ((const float4*)score)[tid];
    v.x *= scale; v.y *= scale; v.z *= scale; v.w *= scale;
    float mx = fmaxf(fmaxf(v.x, v.y), fmaxf(v.z, v.w));
    red[tid] = mx; __syncthreads();
    for (int s = 128; s > 0; s >>= 1) {
        if (tid < s) red[tid] = fmaxf(red[tid], red[tid+s]);
        __syncthreads();
    }
    mx = red[0]; __syncthreads();
    float4 e;
    e.x = expf(v.x - mx); e.y = expf(v.y - mx);
    e.z = expf(v.z - mx); e.w = expf(v.w - mx);
    red[tid] = e.x + e.y + e.z + e.w; __syncthreads();
    for (int s = 128; s > 0; s >>= 1) {
        if (tid < s) red[tid] += red[tid+s];
        __syncthreads();
    }
    const float inv = 1.f / red[0];
    e.x *= inv; e.y *= inv; e.z *= inv; e.w *= inv;
    ((float4*)wts)[tid] = e;
}

// K5: state2 = phi_Q @ weights. Block per row d.
__global__ __launch_bounds__(256) void k_state2(
    const float* __restrict__ cosQ, const float* __restrict__ sinQ,
    const float* __restrict__ wts,
    float* __restrict__ s2re, float* __restrict__ s2im)
{
    __shared__ float r1[256], r2[256];
    const int d = blockIdx.x, tid = threadIdx.x;
    float4 w = ((const float4*)wts)[tid];
    float4 a = ((const float4*)(cosQ + (size_t)d * N_STATES))[tid];
    float4 b = ((const float4*)(sinQ + (size_t)d * N_STATES))[tid];
    r1[tid] = a.x*w.x + a.y*w.y + a.z*w.z + a.w*w.w;
    r2[tid] = b.x*w.x + b.y*w.y + b.z*w.z + b.w*w.w;
    __syncthreads();
    for (int s = 128; s > 0; s >>= 1) {
        if (tid < s) { r1[tid] += r1[tid+s]; r2[tid] += r2[tid+s]; }
        __syncthreads();
    }
    if (tid == 0) { s2re[d] = r1[0]; s2im[d] = r2[0]; }
}

// K6 (fp16 path): obs_acc[o] += sum_{d in chunk of 64} re*c + im*s from the
// interleaved fp16 copy (one 16B load per 4 obs columns). Mh (164 MB) is
// L3-resident from pass 1 -> mostly Infinity-Cache hits.
__global__ __launch_bounds__(256) void k_obs_acc_h(
    const uint4* __restrict__ Mh,
    const float* __restrict__ s2re, const float* __restrict__ s2im,
    float* __restrict__ obs_acc)
{
    __shared__ float c_s[64], s_s[64];
    const int tid = threadIdx.x;
    const int dbase = blockIdx.y * 64;
    if (tid < 64) { c_s[tid] = s2re[dbase + tid]; s_s[tid] = s2im[dbase + tid]; }
    __syncthreads();
    const int idx = blockIdx.x * 256 + tid;   // float4-column group
    if (idx >= N_OBS4) return;
    const uint4* p = Mh + (size_t)dbase * N_OBS4 + idx;
    float4 acc[4];
    #pragma unroll
    for (int u = 0; u < 4; u++) acc[u] = make_float4(0.f, 0.f, 0.f, 0.f);
    #pragma unroll 8
    for (int j = 0; j < 64; ++j) {
        uint4 u = p[(size_t)j * N_OBS4];
        float cc = c_s[j], ss = s_s[j];
        union { unsigned u; __half2 h; } w0, w1, w2, w3;
        w0.u = u.x; w1.u = u.y; w2.u = u.z; w3.u = u.w;
        float2 f0 = __half22float2(w0.h);
        float2 f1 = __half22float2(w1.h);
        float2 f2 = __half22float2(w2.h);
        float2 f3 = __half22float2(w3.h);
        acc[j & 3].x += f0.x*cc + f0.y*ss;
        acc[j & 3].y += f1.x*cc + f1.y*ss;
        acc[j & 3].z += f2.x*cc + f2.y*ss;
        acc[j & 3].w += f3.x*cc + f3.y*ss;
    }
    float4 t;
    t.x = (acc[0].x + acc[1].x) + (acc[2].x + acc[3].x);
    t.y = (acc[0].y + acc[1].y) + (acc[2].y + acc[3].y);
    t.z = (acc[0].z + acc[1].z) + (acc[2].z + acc[3].z);
    t.w = (acc[0].w + acc[1].w) + (acc[2].w + acc[3].w);
    atomicAdd(&obs_acc[idx*4 + 0], t.x);
    atomicAdd(&obs_acc[idx*4 + 1], t.y);
    atomicAdd(&obs_acc[idx*4 + 2], t.z);
    atomicAdd(&obs_acc[idx*4 + 3], t.w);
}

// K6 (fp32 fallback, used only if workspace can't hold Mh)
__global__ __launch_bounds__(256) void k_obs_acc_f32(
    const float* __restrict__ Mre, const float* __restrict__ Mim,
    const float* __restrict__ s2re, const float* __restrict__ s2im,
    float* __restrict__ obs_acc)
{
    __shared__ float c_s[64], s_s[64];
    const int tid = threadIdx.x;
    const int dbase = blockIdx.y * 64;
    if (tid < 64) { c_s[tid] = s2re[dbase + tid]; s_s[tid] = s2im[dbase + tid]; }
    __syncthreads();
    const int idx = blockIdx.x * 256 + tid;
    if (idx >= N_OBS4) return;
    float4 acc[4];
    #pragma unroll
    for (int u = 0; u < 4; u++) acc[u] = make_float4(0.f, 0.f, 0.f, 0.f);
    #pragma unroll 8
    for (int j = 0; j < 64; j++) {
        size_t base = ((size_t)(dbase + j) * N_OBS4 + idx) * 4;
        v4f a = ntload4(Mre + base);
        v4f b = ntload4(Mim + base);
        float cc = c_s[j], ss = s_s[j];
        acc[j & 3].x += a.x*cc + b.x*ss;
        acc[j & 3].y += a.y*cc + b.y*ss;
        acc[j & 3].z += a.z*cc + b.z*ss;
        acc[j & 3].w += a.w*cc + b.w*ss;
    }
    float4 t;
    t.x = (acc[0].x + acc[1].x) + (acc[2].x + acc[3].x);
    t.y = (acc[0].y + acc[1].y) + (acc[2].y + acc[3].y);
    t.z = (acc[0].z + acc[1].z) + (acc[2].z + acc[3].z);
    t.w = (acc[0].w + acc[1].w) + (acc[2].w + acc[3].w);
    atomicAdd(&obs_acc[idx*4 + 0], t.x);
    atomicAdd(&obs_acc[idx*4 + 1], t.y);
    atomicAdd(&obs_acc[idx*4 + 2], t.z);
    atomicAdd(&obs_acc[idx*4 + 3], t.w);
}

// K7: dot0 = Re(s0 . conj(s2)); out = softmax((0.9*obs_acc + obs*dot0)/2048).
__global__ __launch_bounds__(1024) void k_softmax_obs(
    const float* __restrict__ obs_acc, const float* __restrict__ obs,
    const float* __restrict__ s0re, const float* __restrict__ s0im,
    const float* __restrict__ s2re, const float* __restrict__ s2im,
    float* __restrict__ out)
{
    __shared__ float red[1024];
    const int tid = threadIdx.x;
    float dp = 0.f;
    #pragma unroll
    for (int i = 0; i < 2; i++) {
        int d = tid + i * 1024;
        dp += s0re[d] * s2re[d] + s0im[d] * s2im[d];
    }
    red[tid] = dp; __syncthreads();
    for (int s = 512; s > 0; s >>= 1) {
        if (tid < s) red[tid] += red[tid+s];
        __syncthreads();
    }
    const float d0 = red[0];
    __syncthreads();
    const float scale = 1.f / (float)RFD;
    float vals[20];
    float mx = -3.402823466e+38f;
    #pragma unroll
    for (int i = 0; i < 20; i++) {
        int idx = tid + i * 1024;
        if (idx < N_OBS) {
            float sc = (DECAY * obs_acc[idx] + obs[idx] * d0) * scale;
            vals[i] = sc;
            mx = fmaxf(mx, sc);
        } else vals[i] = -3.402823466e+38f;
    }
    red[tid] = mx; __syncthreads();
    for (int s = 512; s > 0; s >>= 1) {
        if (tid < s) red[tid] = fmaxf(red[tid], red[tid+s]);
        __syncthreads();
    }
    mx = red[0]; __syncthreads();
    float sum = 0.f;
    #pragma unroll
    for (int i = 0; i < 20; i++) {
        int idx = tid + i * 1024;
        if (idx < N_OBS) {
            vals[i] = expf(vals[i] - mx);
            sum += vals[i];
        }
    }
    red[tid] = sum; __syncthreads();
    for (int s = 512; s > 0; s >>= 1) {
        if (tid < s) red[tid] += red[tid+s];
        __syncthreads();
    }
    const float inv = 1.f / red[0];
    #pragma unroll
    for (int i = 0; i < 20; i++) {
        int idx = tid + i * 1024;
        if (idx < N_OBS) out[idx] = vals[i] * inv;
    }
}

extern "C" void kernel_launch(void* const* d_in, const int* in_sizes, int n_in,
                              void* d_out, int out_size, void* d_ws, size_t ws_size,
                              hipStream_t stream) {
    const float* Q      = (const float*)d_in[0];  // [256,1024]
    const float* V      = (const float*)d_in[1];  // [256,64]
    const float* W      = (const float*)d_in[2];  // [2048,256]
    const float* Mre    = (const float*)d_in[3];  // [2048,20000]
    const float* Mim    = (const float*)d_in[4];  // [2048,20000]
    const float* obs    = (const float*)d_in[5];  // [20000]
    const float* action = (const float*)d_in[6];  // [64]
    float* out = (float*)d_out;                   // [20000]
    float* ws  = (float*)d_ws;

    if (ws_size < (size_t)WS_BASE_FLOATS * sizeof(float)) return;
    const int fp16path = ws_size >= (size_t)WS_FP16_FLOATS * sizeof(float);

    float* score = ws + OFF_SCORE;
    float* oacc  = ws + OFF_OBSACC;
    float* s0re  = ws + OFF_S0RE;
    float* s0im  = ws + OFF_S0IM;
    float* s2re  = ws + OFF_S2RE;
    float* s2im  = ws + OFF_S2IM;
    float* wts   = ws + OFF_WTS;
    float* vws   = ws + OFF_VWS;
    float* cosQ  = ws + OFF_COSQ;
    float* sinQ  = ws + OFF_SINQ;
    uint4* Mh    = (uint4*)(ws + OFF_MH);

    // zero the atomic accumulators (score, obs_acc) in one contiguous memset
    hipMemsetAsync(ws, 0, (size_t)ZERO_CNT * sizeof(float), stream);

    k_fused<<<NB_FUSED, 256, 0, stream>>>(Mre, Mim, obs, W, Q, V, action,
                                          cosQ, sinQ, s0re, s0im, vws,
                                          Mh, fp16path);
    k_score<<<dim3(4, 64), 256, 0, stream>>>(cosQ, sinQ, W, vws, s0re, s0im, score);
    k_softmax_w<<<1, 256, 0, stream>>>(score, wts);
    k_state2<<<RFD, 256, 0, stream>>>(cosQ, sinQ, wts, s2re, s2im);
    if (fp16path)
        k_obs_acc_h<<<dim3(20, 32), 256, 0, stream>>>(Mh, s2re, s2im, oacc);
    else
        k_obs_acc_f32<<<dim3(20, 32), 256, 0, stream>>>(Mre, Mim, s2re, s2im, oacc);
    k_softmax_obs<<<1, 1024, 0, stream>>>(oacc, obs, s0re, s0im, s2re, s2im, out);
}